// Round 5
// baseline (273.140 us; speedup 1.0000x reference)
//
#include <hip/hip_runtime.h>

// ChebyKANLayer: y[t,o] = bias[o] + sum_k A[t,k]*B[k,o], K=8192, k=i*8+(d-1), d=1..8.
// R5: tanh precomputed to ws (f32, deinterleaved [r][(i>>1)+(i&1)*512]) -> hot loop
// chain = 7 fma + cvt only, float2 row-pairing for v_pk_fma_f32. A-frags in registers
// (mfma_32x32x16), B via global_load_lds, conflict-free [k-chunk][col] LDS layout.

typedef __bf16 bf16;
typedef __bf16 bf16x8 __attribute__((ext_vector_type(8)));
typedef float f32x2 __attribute__((ext_vector_type(2)));
typedef float f32x4 __attribute__((ext_vector_type(4)));
typedef float f32x16 __attribute__((ext_vector_type(16)));

__device__ __forceinline__ void g2lds16(const void* g, void* l) {
  __builtin_amdgcn_global_load_lds(
      (const __attribute__((address_space(1))) unsigned int*)g,
      (__attribute__((address_space(3))) unsigned int*)l, 16, 0, 0);
}

__device__ __forceinline__ float fast_tanh(float a) {
  float e = __expf(a + a);
  return 1.f - 2.f * __builtin_amdgcn_rcpf(e + 1.f);   // saturating, NaN-free
}

// ---- prep A: th[r][(i>>1)+(i&1)*512] = tanh(x[r][i]) ----
__global__ __launch_bounds__(256)
void cheby_tanh(const float* __restrict__ x, float* __restrict__ th) {
  const int gid = blockIdx.x * 256 + threadIdx.x;
  const int r = gid >> 8, c = gid & 255;                // 4 consecutive i per thread
  f32x4 v = *(const f32x4*)(x + (size_t)r * 1024 + c * 4);
  f32x4 t;
  #pragma unroll
  for (int j = 0; j < 4; ++j) t[j] = fast_tanh(v[j]);
  *(f32x2*)(th + (size_t)r * 1024 + c * 2)       = (f32x2){t.x, t.z};  // even i
  *(f32x2*)(th + (size_t)r * 1024 + 512 + c * 2) = (f32x2){t.y, t.w};  // odd i
}

// ---- prep B: Bt entry (nb, s, c, col) = bf16(C[i=s*8+c][o=nb*128+col][d=1..8]) ----
__global__ __launch_bounds__(256)
void cheby_prep(const float* __restrict__ C, bf16* __restrict__ Bt,
                float* __restrict__ bias) {
  __shared__ float tile[32][292];
  const int i0 = blockIdx.x * 32, o0 = blockIdx.y * 32;
  const int tid = threadIdx.x;
  {
    const int r = tid >> 3, seg = tid & 7;
    const float* src = C + (size_t)(i0 + r) * 9216 + (size_t)o0 * 9 + seg * 36;
    float* dst = &tile[r][seg * 36];
    #pragma unroll
    for (int v = 0; v < 9; ++v) *(f32x4*)(dst + v * 4) = *(const f32x4*)(src + v * 4);
  }
  __syncthreads();
  #pragma unroll
  for (int j = 0; j < 4; ++j) {
    int e = tid + 256 * j;
    int il = e >> 5, ol = e & 31;
    int i = i0 + il, o = o0 + ol;
    bf16x8 v;
    #pragma unroll
    for (int d = 0; d < 8; ++d) v[d] = (bf16)tile[il][ol * 9 + 1 + d];
    size_t idx16 = ((size_t)((o >> 7) * 128 + (i >> 3)) * 8 + (i & 7)) * 128 + (o & 127);
    *(bf16x8*)&Bt[idx16 * 8] = v;
  }
  if (tid < 32) {
    float s = 0.f;
    #pragma unroll
    for (int i = 0; i < 32; ++i) s += tile[i][tid * 9];
    atomicAdd(&bias[o0 + tid], s);
  }
}

// ---- fused basis-gen + GEMM: block 128x128, 256 thr (2x2 waves, wave 64x64), 2 blk/CU.
// PRE: xsrc = deinterleaved tanh (f32).  !PRE: xsrc = raw x, tanh in-kernel (R4 path).
template <bool PRE>
__global__ __launch_bounds__(256, 2)
void cheby_gemm(const float* __restrict__ xsrc, const bf16* __restrict__ Bt,
                const float* __restrict__ bias, float* __restrict__ out) {
  __shared__ bf16 Bs[2][8192];                     // 2 x 16 KB: [c 0..7][col 0..127][8]

  const int tid  = threadIdx.x;
  const int lane = tid & 63, w = tid >> 6;
  const int wm = w >> 1, wn = w & 1;
  const int nb = blockIdx.x & 7, mb = blockIdx.x >> 3;
  const int t0 = mb * 128, o0 = nb * 128;
  const int ml = lane & 31, h = lane >> 5;

  // row pointers: PRE -> th row + h-half base; !PRE -> x row base
  const float* xr0 = xsrc + (size_t)(t0 + wm * 64 + ml) * 1024 + (PRE ? h * 512 : 0);
  const float* xr1 = xr0 + 32 * 1024;

  const bf16* btw = Bt + ((size_t)nb * 128 * 1024 + (size_t)w * 256 + lane) * 8;

  f32x16 acc[2][2];
  #pragma unroll
  for (int a = 0; a < 2; ++a)
    #pragma unroll
    for (int b = 0; b < 2; ++b)
      #pragma unroll
      for (int r = 0; r < 16; ++r) acc[a][b][r] = 0.f;

  f32x4 xv[4];
  if (PRE) {                                       // one f32x4 per row: the 4 ks seeds
    xv[0] = *(const f32x4*)(xr0);
    xv[1] = *(const f32x4*)(xr1);
  } else {
    xv[0] = *(const f32x4*)(xr0); xv[1] = *(const f32x4*)(xr0 + 4);
    xv[2] = *(const f32x4*)(xr1); xv[3] = *(const f32x4*)(xr1 + 4);
  }

  #pragma unroll
  for (int b = 0; b < 4; ++b)
    g2lds16(btw + (size_t)b * 64 * 8, &Bs[0][(w * 256 + b * 64) * 8]);

  #pragma unroll 1
  for (int s = 0; s < 128; ++s) {
    const int bi = s & 1;
    __syncthreads();                               // Bs[bi] landed; Bs[bi^1] free
    if (s < 127) {
      const bf16* g = btw + (size_t)(s + 1) * 1024 * 8;
      #pragma unroll
      for (int b = 0; b < 4; ++b)
        g2lds16(g + (size_t)b * 64 * 8, &Bs[bi ^ 1][(w * 256 + b * 64) * 8]);
    }

    bf16x8 afr[2][4];
    if (PRE) {
      f32x4 seeds0 = xv[0], seeds1 = xv[1];
      if (s < 127) {                               // prefetch next stage's seeds
        xv[0] = *(const f32x4*)(xr0 + (s + 1) * 4);
        xv[1] = *(const f32x4*)(xr1 + (s + 1) * 4);
      }
      #pragma unroll
      for (int ks = 0; ks < 4; ++ks) {             // row-paired chains -> v_pk_fma_f32
        f32x2 t  = {seeds0[ks], seeds1[ks]};
        f32x2 t2 = t + t;
        f32x2 prev = {1.f, 1.f}, cur = t;
        f32x2 T[8];
        T[0] = cur;
        #pragma unroll
        for (int j = 1; j < 8; ++j) {
          f32x2 nx = t2 * cur - prev;              // contracts to pk_fma
          prev = cur; cur = nx;
          T[j] = cur;
        }
        #pragma unroll
        for (int j = 0; j < 8; ++j) {
          afr[0][ks][j] = (bf16)T[j].x;
          afr[1][ks][j] = (bf16)T[j].y;
        }
      }
    } else {
      float xs[2][8];
      #pragma unroll
      for (int v = 0; v < 4; ++v) {
        xs[v >> 1][(v & 1) * 4 + 0] = xv[v].x; xs[v >> 1][(v & 1) * 4 + 1] = xv[v].y;
        xs[v >> 1][(v & 1) * 4 + 2] = xv[v].z; xs[v >> 1][(v & 1) * 4 + 3] = xv[v].w;
      }
      if (s < 127) {
        xv[0] = *(const f32x4*)(xr0 + (s + 1) * 8);
        xv[1] = *(const f32x4*)(xr0 + (s + 1) * 8 + 4);
        xv[2] = *(const f32x4*)(xr1 + (s + 1) * 8);
        xv[3] = *(const f32x4*)(xr1 + (s + 1) * 8 + 4);
      }
      #pragma unroll
      for (int r = 0; r < 2; ++r)
        #pragma unroll
        for (int ks = 0; ks < 4; ++ks) {
          float a  = h ? xs[r][2 * ks + 1] : xs[r][2 * ks];
          float th = fast_tanh(a);
          float t2 = th + th;
          bf16x8 f;
          f[0] = (bf16)th;
          float prev = 1.f, cur = th;
          #pragma unroll
          for (int j = 1; j < 8; ++j) {
            float nx = __builtin_fmaf(t2, cur, -prev);
            prev = cur; cur = nx;
            f[j] = (bf16)cur;
          }
          afr[r][ks] = f;
        }
    }

    #pragma unroll
    for (int ks = 0; ks < 4; ++ks) {
      const int ce = ((ks * 2 + h) * 128 + wn * 64 + ml) * 8;   // half-wave contiguous
      bf16x8 b0 = *(const bf16x8*)&Bs[bi][ce];
      bf16x8 b1 = *(const bf16x8*)&Bs[bi][ce + 32 * 8];
      acc[0][0] = __builtin_amdgcn_mfma_f32_32x32x16_bf16(afr[0][ks], b0, acc[0][0], 0, 0, 0);
      acc[0][1] = __builtin_amdgcn_mfma_f32_32x32x16_bf16(afr[0][ks], b1, acc[0][1], 0, 0, 0);
      acc[1][0] = __builtin_amdgcn_mfma_f32_32x32x16_bf16(afr[1][ks], b0, acc[1][0], 0, 0, 0);
      acc[1][1] = __builtin_amdgcn_mfma_f32_32x32x16_bf16(afr[1][ks], b1, acc[1][1], 0, 0, 0);
    }
  }

  // epilogue: 32x32 C/D layout col=lane&31, row=(reg&3)+8*(reg>>2)+4*(lane>>5)
  const float bv0 = bias[o0 + wn * 64 + ml];
  const float bv1 = bias[o0 + wn * 64 + 32 + ml];
  #pragma unroll
  for (int mt = 0; mt < 2; ++mt)
    #pragma unroll
    for (int r = 0; r < 16; ++r) {
      int row = t0 + wm * 64 + mt * 32 + (r & 3) + 8 * (r >> 2) + 4 * h;
      float* po = out + (size_t)row * 1024 + o0 + wn * 64 + ml;
      po[0]  = acc[mt][0][r] + bv0;
      po[32] = acc[mt][1][r] + bv1;
    }
}

// ---- fallback (ws too small) — correct, slow, should never run
__global__ __launch_bounds__(256)
void cheby_naive(const float* __restrict__ x, const float* __restrict__ C,
                 float* __restrict__ out) {
  const int t = blockIdx.x, tid = threadIdx.x;
  float acc[4] = {0.f, 0.f, 0.f, 0.f};
  for (int i = 0; i < 1024; ++i) {
    float th = tanhf(x[(size_t)t * 1024 + i]);
    float T[9]; T[0] = 1.f; T[1] = th;
    #pragma unroll
    for (int d = 2; d < 9; ++d) T[d] = 2.f * th * T[d - 1] - T[d - 2];
    #pragma unroll
    for (int j = 0; j < 4; ++j) {
      const float* cp = &C[((size_t)i * 1024 + tid + j * 256) * 9];
      float s = 0.f;
      #pragma unroll
      for (int d = 0; d < 9; ++d) s += T[d] * cp[d];
      acc[j] += s;
    }
  }
  #pragma unroll
  for (int j = 0; j < 4; ++j) out[(size_t)t * 1024 + tid + j * 256] = acc[j];
}

extern "C" void kernel_launch(void* const* d_in, const int* in_sizes, int n_in,
                              void* d_out, int out_size, void* d_ws, size_t ws_size,
                              hipStream_t stream) {
  (void)in_sizes; (void)n_in; (void)out_size;
  const float* x = (const float*)d_in[0];
  const float* C = (const float*)d_in[1];
  float* out = (float*)d_out;

  const size_t bt_bytes   = (size_t)8 * 128 * 1024 * 8 * sizeof(bf16);  // 16.78 MB
  const size_t bias_bytes = 1024 * sizeof(float);
  const size_t th_bytes   = (size_t)8192 * 1024 * sizeof(float);        // 33.55 MB

  if (ws_size >= bt_bytes + bias_bytes + th_bytes) {
    bf16*  Bt   = (bf16*)d_ws;
    float* bias = (float*)((char*)d_ws + bt_bytes);
    float* th   = (float*)((char*)d_ws + bt_bytes + bias_bytes);
    hipMemsetAsync(bias, 0, bias_bytes, stream);
    cheby_tanh<<<8192, 256, 0, stream>>>(x, th);
    cheby_prep<<<dim3(32, 32), 256, 0, stream>>>(C, Bt, bias);
    cheby_gemm<true><<<512, 256, 0, stream>>>(th, Bt, bias, out);
  } else if (ws_size >= bt_bytes + bias_bytes) {
    bf16*  Bt   = (bf16*)d_ws;
    float* bias = (float*)((char*)d_ws + bt_bytes);
    hipMemsetAsync(bias, 0, bias_bytes, stream);
    cheby_prep<<<dim3(32, 32), 256, 0, stream>>>(C, Bt, bias);
    cheby_gemm<false><<<512, 256, 0, stream>>>(x, Bt, bias, out);
  } else {
    cheby_naive<<<8192, 256, 0, stream>>>(x, C, out);
  }
}

// Round 6
// 269.182 us; speedup vs baseline: 1.0147x; 1.0147x over previous
//
#include <hip/hip_runtime.h>

// ChebyKANLayer: y[t,o] = bias[o] + sum_k A[t,k]*B[k,o], K=8192, k=i*8+(d-1), d=1..8.
// R6: (a) A-gen software-pipelined -- stage s+1's fragments generated in the MFMA
// shadow of stage s (afrA/afrB reg double-buffer, x2-unrolled loop);
// (b) single fused prep kernel (tanh + Bt + bias partials), bias reduced in epilogue.

typedef __bf16 bf16;
typedef __bf16 bf16x8 __attribute__((ext_vector_type(8)));
typedef float f32x2 __attribute__((ext_vector_type(2)));
typedef float f32x4 __attribute__((ext_vector_type(4)));
typedef float f32x16 __attribute__((ext_vector_type(16)));

__device__ __forceinline__ void g2lds16(const void* g, void* l) {
  __builtin_amdgcn_global_load_lds(
      (const __attribute__((address_space(1))) unsigned int*)g,
      (__attribute__((address_space(3))) unsigned int*)l, 16, 0, 0);
}

__device__ __forceinline__ float fast_tanh(float a) {
  float e = __expf(a + a);
  return 1.f - 2.f * __builtin_amdgcn_rcpf(e + 1.f);   // saturating, NaN-free
}

// ---- fused prep: blocks [0,1024) build Bt + bias partials; [1024,9216) tanh rows.
// Bt entry (nb, s, c, col) = bf16(C[i=s*8+c][o=nb*128+col][d=1..8]).
// th[r][(i>>1)+(i&1)*512] = tanh(x[r][i]).  bias_p[p][o] = sum_{i in p-block} C[i][o][0].
__global__ __launch_bounds__(256)
void cheby_prep(const float* __restrict__ x, const float* __restrict__ C,
                bf16* __restrict__ Bt, float* __restrict__ bias_p,
                float* __restrict__ th) {
  const int bid = blockIdx.x, tid = threadIdx.x;
  if (bid >= 1024) {                               // ---- tanh branch: one token row
    const int r = bid - 1024;
    f32x4 v = *(const f32x4*)(x + (size_t)r * 1024 + tid * 4);
    f32x4 t;
    #pragma unroll
    for (int j = 0; j < 4; ++j) t[j] = fast_tanh(v[j]);
    *(f32x2*)(th + (size_t)r * 1024 + tid * 2)       = (f32x2){t.x, t.z};  // even i
    *(f32x2*)(th + (size_t)r * 1024 + 512 + tid * 2) = (f32x2){t.y, t.w};  // odd i
    return;
  }
  __shared__ float tile[32][292];
  const int i0 = (bid >> 5) * 32, o0 = (bid & 31) * 32;
  {
    const int r = tid >> 3, seg = tid & 7;
    const float* src = C + (size_t)(i0 + r) * 9216 + (size_t)o0 * 9 + seg * 36;
    float* dst = &tile[r][seg * 36];
    #pragma unroll
    for (int v = 0; v < 9; ++v) *(f32x4*)(dst + v * 4) = *(const f32x4*)(src + v * 4);
  }
  __syncthreads();
  #pragma unroll
  for (int j = 0; j < 4; ++j) {
    int e = tid + 256 * j;
    int il = e >> 5, ol = e & 31;
    int i = i0 + il, o = o0 + ol;
    bf16x8 v;
    #pragma unroll
    for (int d = 0; d < 8; ++d) v[d] = (bf16)tile[il][ol * 9 + 1 + d];
    size_t idx16 = ((size_t)((o >> 7) * 128 + (i >> 3)) * 8 + (i & 7)) * 128 + (o & 127);
    *(bf16x8*)&Bt[idx16 * 8] = v;
  }
  if (tid < 32) {
    float s = 0.f;
    #pragma unroll
    for (int i = 0; i < 32; ++i) s += tile[i][tid * 9];
    bias_p[(size_t)(bid >> 5) * 1024 + o0 + tid] = s;   // partial, no atomics
  }
}

// ---- fused basis-gen + GEMM: block 128x128, 256 thr (2x2 waves, wave 64x64), 2 blk/CU.
__global__ __launch_bounds__(256, 2)
void cheby_gemm(const float* __restrict__ th, const bf16* __restrict__ Bt,
                const float* __restrict__ bias_p, float* __restrict__ out) {
  __shared__ bf16 Bs[2][8192];                     // 2 x 16 KB: [c 0..7][col 0..127][8]

  const int tid  = threadIdx.x;
  const int lane = tid & 63, w = tid >> 6;
  const int wm = w >> 1, wn = w & 1;
  const int nb = blockIdx.x & 7, mb = blockIdx.x >> 3;
  const int t0 = mb * 128, o0 = nb * 128;
  const int ml = lane & 31, h = lane >> 5;

  const float* xr0 = th + (size_t)(t0 + wm * 64 + ml) * 1024 + h * 512;
  const float* xr1 = xr0 + 32 * 1024;
  const bf16* btw = Bt + ((size_t)nb * 128 * 1024 + (size_t)w * 256 + lane) * 8;

  f32x16 acc[2][2];
  #pragma unroll
  for (int a = 0; a < 2; ++a)
    #pragma unroll
    for (int b = 0; b < 2; ++b)
      #pragma unroll
      for (int r = 0; r < 16; ++r) acc[a][b][r] = 0.f;

  bf16x8 afrA[2][4], afrB[2][4];
  f32x4 xv0, xv1;                                  // seeds for the NEXT stage to generate

  auto gen = [&](bf16x8 (&dst)[2][4], f32x4 s0, f32x4 s1) {
    #pragma unroll
    for (int ks = 0; ks < 4; ++ks) {               // row-paired chains -> v_pk_fma_f32
      f32x2 t  = {s0[ks], s1[ks]};
      f32x2 t2 = t + t;
      f32x2 prev = {1.f, 1.f}, cur = t;
      #pragma unroll
      for (int j = 0; j < 8; ++j) {
        dst[0][ks][j] = (bf16)cur.x;
        dst[1][ks][j] = (bf16)cur.y;
        f32x2 nx = t2 * cur - prev;
        prev = cur; cur = nx;
      }
    }
  };

  // prologue: gen stage 0 now; seeds(1) into xv; stage-0 B -> buf 0
  {
    f32x4 s0 = *(const f32x4*)(xr0), s1 = *(const f32x4*)(xr1);
    gen(afrA, s0, s1);
    xv0 = *(const f32x4*)(xr0 + 4);
    xv1 = *(const f32x4*)(xr1 + 4);
  }
  #pragma unroll
  for (int b = 0; b < 4; ++b)
    g2lds16(btw + (size_t)b * 64 * 8, &Bs[0][(w * 256 + b * 64) * 8]);

  auto stage = [&](int s, int bi, bf16x8 (&cur)[2][4], bf16x8 (&nxt)[2][4]) {
    __syncthreads();                               // Bs[bi] landed; Bs[bi^1] free
    if (s < 127) {                                 // stage s+1 B -> other buffer
      const bf16* g = btw + (size_t)(s + 1) * 8192;
      #pragma unroll
      for (int b = 0; b < 4; ++b)
        g2lds16(g + (size_t)b * 64 * 8, &Bs[bi ^ 1][(w * 256 + b * 64) * 8]);
    }
    bf16x8 bfr[4][2];
    #pragma unroll
    for (int ks = 0; ks < 4; ++ks) {
      const int ce = ((ks * 2 + h) * 128 + wn * 64 + ml) * 8;   // half-wave contiguous
      bfr[ks][0] = *(const bf16x8*)&Bs[bi][ce];
      bfr[ks][1] = *(const bf16x8*)&Bs[bi][ce + 32 * 8];
    }
    if (s < 127) {
      gen(nxt, xv0, xv1);                          // VALU for s+1: fills MFMA shadow
      if (s < 126) {                               // seeds(s+2) for the next gen
        xv0 = *(const f32x4*)(xr0 + (s + 2) * 4);
        xv1 = *(const f32x4*)(xr1 + (s + 2) * 4);
      }
    }
    #pragma unroll
    for (int ks = 0; ks < 4; ++ks) {
      acc[0][0] = __builtin_amdgcn_mfma_f32_32x32x16_bf16(cur[0][ks], bfr[ks][0], acc[0][0], 0, 0, 0);
      acc[0][1] = __builtin_amdgcn_mfma_f32_32x32x16_bf16(cur[0][ks], bfr[ks][1], acc[0][1], 0, 0, 0);
      acc[1][0] = __builtin_amdgcn_mfma_f32_32x32x16_bf16(cur[1][ks], bfr[ks][0], acc[1][0], 0, 0, 0);
      acc[1][1] = __builtin_amdgcn_mfma_f32_32x32x16_bf16(cur[1][ks], bfr[ks][1], acc[1][1], 0, 0, 0);
    }
  };

  #pragma unroll 1
  for (int s2 = 0; s2 < 64; ++s2) {                // x2-unrolled: static buffer indices
    stage(2 * s2,     0, afrA, afrB);
    stage(2 * s2 + 1, 1, afrB, afrA);
  }

  // epilogue: bias = sum of 32 partials; C/D layout col=lane&31, row=(reg&3)+8*(reg>>2)+4*h
  const int c0 = o0 + wn * 64 + ml;
  float bv0 = 0.f, bv1 = 0.f;
  #pragma unroll
  for (int p = 0; p < 32; ++p) {
    bv0 += bias_p[(size_t)p * 1024 + c0];
    bv1 += bias_p[(size_t)p * 1024 + c0 + 32];
  }
  #pragma unroll
  for (int mt = 0; mt < 2; ++mt)
    #pragma unroll
    for (int r = 0; r < 16; ++r) {
      int row = t0 + wm * 64 + mt * 32 + (r & 3) + 8 * (r >> 2) + 4 * h;
      float* po = out + (size_t)row * 1024 + c0;
      po[0]  = acc[mt][0][r] + bv0;
      po[32] = acc[mt][1][r] + bv1;
    }
}

// ---- fallback (ws too small) — correct, slow, should never run
__global__ __launch_bounds__(256)
void cheby_naive(const float* __restrict__ x, const float* __restrict__ C,
                 float* __restrict__ out) {
  const int t = blockIdx.x, tid = threadIdx.x;
  float acc[4] = {0.f, 0.f, 0.f, 0.f};
  for (int i = 0; i < 1024; ++i) {
    float th = tanhf(x[(size_t)t * 1024 + i]);
    float T[9]; T[0] = 1.f; T[1] = th;
    #pragma unroll
    for (int d = 2; d < 9; ++d) T[d] = 2.f * th * T[d - 1] - T[d - 2];
    #pragma unroll
    for (int j = 0; j < 4; ++j) {
      const float* cp = &C[((size_t)i * 1024 + tid + j * 256) * 9];
      float s = 0.f;
      #pragma unroll
      for (int d = 0; d < 9; ++d) s += T[d] * cp[d];
      acc[j] += s;
    }
  }
  #pragma unroll
  for (int j = 0; j < 4; ++j) out[(size_t)t * 1024 + tid + j * 256] = acc[j];
}

extern "C" void kernel_launch(void* const* d_in, const int* in_sizes, int n_in,
                              void* d_out, int out_size, void* d_ws, size_t ws_size,
                              hipStream_t stream) {
  (void)in_sizes; (void)n_in; (void)out_size;
  const float* x = (const float*)d_in[0];
  const float* C = (const float*)d_in[1];
  float* out = (float*)d_out;

  const size_t bt_bytes = (size_t)8 * 128 * 1024 * 8 * sizeof(bf16);  // 16.78 MB
  const size_t bp_bytes = (size_t)32 * 1024 * sizeof(float);          // 128 KB
  const size_t th_bytes = (size_t)8192 * 1024 * sizeof(float);        // 33.55 MB

  if (ws_size >= bt_bytes + bp_bytes + th_bytes) {
    bf16*  Bt     = (bf16*)d_ws;
    float* bias_p = (float*)((char*)d_ws + bt_bytes);
    float* th     = (float*)((char*)d_ws + bt_bytes + bp_bytes);
    cheby_prep<<<9216, 256, 0, stream>>>(x, C, Bt, bias_p, th);
    cheby_gemm<<<512, 256, 0, stream>>>(th, Bt, bias_p, out);
  } else {
    cheby_naive<<<8192, 256, 0, stream>>>(x, C, out);
  }
}